// Round 7
// baseline (1498.012 us; speedup 1.0000x reference)
//
#include <hip/hip_runtime.h>
#include <hip/hip_bf16.h>
#include <math.h>

// GraphLSTM (binary TreeLSTM), 64 trees x 2047 nodes, H=E=256, C=104.
// Round 6 == round 5 (GPU acquisition timed out; no bench evidence).
// Round 5: latency fix. No unroll-1 (full unroll -> load pipelining as in
// round 1). hch LDS deleted: GEMM2 A-frags direct from global in MFMA layout
// (64B-line exact), B shared across both M-tiles. cin in registers, delivered
// to GEMM1 epilogue via the round-2-verified g-group shuffle. LDS = xcat only
// (33.3 KB internal / 16.9 KB leaf) -> 12-16 waves/CU.

#define NTREES 64
#define TDEPTH 11
#define NPT    2047
#define HD     256
#define H3     768
#define NCLS   104

typedef short v8s __attribute__((ext_vector_type(8)));
typedef float v4f __attribute__((ext_vector_type(4)));
typedef unsigned short u16;
typedef unsigned int   u32;

__device__ __forceinline__ float bfLo(u32 u) {
    return __builtin_bit_cast(float, u << 16);
}
__device__ __forceinline__ float bfHi(u32 u) {
    return __builtin_bit_cast(float, u & 0xffff0000u);
}
__device__ __forceinline__ u16 f2bf(float f) {
    return __builtin_bit_cast(u16, __float2bfloat16(f));
}
__device__ __forceinline__ u32 pk2(float lo, float hi) {
    return (u32)f2bf(lo) | ((u32)f2bf(hi) << 16);
}
__device__ __forceinline__ float sigm_(float x) {
    return __builtin_amdgcn_rcpf(1.0f + __expf(-x));
}
__device__ __forceinline__ float tanh_(float x) {
    return 1.0f - 2.0f * __builtin_amdgcn_rcpf(__expf(2.0f * x) + 1.0f);
}

// Wcat[n][0:256]=W_iou[n][:], Wcat[n][256:512]=U_iou[n][:] (bf16). Uf bf16.
__global__ __launch_bounds__(256) void prep_weights(
    const float* __restrict__ W_iou, const float* __restrict__ U_iou,
    const float* __restrict__ U_f_w,
    u16* __restrict__ Wcat, u16* __restrict__ Uf)
{
    int tid = blockIdx.x * 256 + threadIdx.x;   // 0..196607
    int n  = tid >> 8;
    int c0 = (tid & 255) * 2;
    float a, b;
    if (c0 < 256) { a = W_iou[n * 256 + c0];       b = W_iou[n * 256 + c0 + 1]; }
    else          { a = U_iou[n * 256 + c0 - 256]; b = U_iou[n * 256 + c0 - 255]; }
    *(u32*)&Wcat[n * 512 + c0] = pk2(a, b);
    if (tid < 32768) {
        int jj = tid >> 7, cc = (tid & 127) * 2;
        *(u32*)&Uf[jj * 256 + cc] = pk2(U_f_w[jj * 256 + cc], U_f_w[jj * 256 + cc + 1]);
    }
}

__global__ __launch_bounds__(256) void emb_to_bf16(
    const float* __restrict__ emb, u16* __restrict__ emb_bf, int n4)
{
    int i = blockIdx.x * 256 + threadIdx.x;
    if (i < n4) {
        const float4 v = ((const float4*)emb)[i];
        uint2 o;
        o.x = pk2(v.x, v.y);
        o.y = pk2(v.z, v.w);
        ((uint2*)emb_bf)[i] = o;
    }
}

// One level. 256 threads = 4 waves, 32 nodes/block. Wave (mt = wv&1,
// h2 = wv>>1): GEMM1 M-tile mt x N-half h2 (p-split); GEMM2 child rows
// 32mt..32mt+31 (2 tiles) x ch-half h2; cin in regs, shuffled to consumers.
template<bool LEAF>
__global__ __launch_bounds__(256, LEAF ? 4 : 3) void level_kernel(
    const int* __restrict__ feat, const u16* __restrict__ emb_bf,
    const u16* __restrict__ Wcat, const u16* __restrict__ Uf,
    const float* __restrict__ b_iou, const float* __restrict__ U_f_b,
    const u16* __restrict__ h_prev, const float* __restrict__ c_prev,
    u16* __restrict__ h_cur, float* __restrict__ c_cur,
    float* __restrict__ hsum, int level)
{
    constexpr int XS = LEAF ? 264 : 520;      // xcat row stride (u16)
    __shared__ __align__(16) u16 xcat[32 * XS];

    const int tid = threadIdx.x;
    const int wv  = tid >> 6;       // 0..3
    const int ln  = tid & 63;
    const int g   = ln >> 4;
    const int r15 = ln & 15;
    const int mt  = wv & 1;         // GEMM1 M-tile
    const int h2  = wv >> 1;        // N / channel half
    const int m0  = blockIdx.x * 32;
    const int L   = 1 << level;

    // ---- stage X (bf16 emb rows) : wave w -> rows 8w..8w+7 ----
    #pragma unroll
    for (int it = 0; it < 8; ++it) {
        const int r    = 8 * wv + it;
        const int m    = m0 + r;
        const int tree = m >> level;
        const int pos  = m & (L - 1);
        const int f    = feat[tree * NPT + (L - 1) + pos];
        const uint2 v = *(const uint2*)(emb_bf + (size_t)f * HD + ln * 4);
        *(uint2*)&xcat[r * XS + ln * 4] = v;
    }

    if constexpr (!LEAF) {
        // ---- stage Hsum = bf16(h_l + h_r) into xcat[:,256:512] ----
        #pragma unroll
        for (int it = 0; it < 8; ++it) {
            const int r = 8 * wv + it;
            const int m = m0 + r;
            const uint2 a = *(const uint2*)(h_prev + (size_t)(2 * m) * HD + ln * 4);
            const uint2 b = *(const uint2*)(h_prev + (size_t)(2 * m + 1) * HD + ln * 4);
            uint2 o;
            o.x = pk2(bfLo(a.x) + bfLo(b.x), bfHi(a.x) + bfHi(b.x));
            o.y = pk2(bfLo(a.y) + bfLo(b.y), bfHi(a.y) + bfHi(b.y));
            *(uint2*)&xcat[r * XS + 256 + ln * 4] = o;
        }
    }
    __syncthreads();

    // ---- GEMM2 + f-epilogue, all in registers ----
    float cinreg[2][8][2];   // [tau][j][q]: node 16mt+8tau+2g+q, ch 16(8h2+j)+r15
    if constexpr (!LEAF) {
        v4f acc2[2][8];
        #pragma unroll
        for (int tau = 0; tau < 2; ++tau)
            #pragma unroll
            for (int j = 0; j < 8; ++j)
                acc2[tau][j] = (v4f){0.f, 0.f, 0.f, 0.f};

        const u16* abase = h_prev + (size_t)(2 * m0 + 32 * mt) * HD;
        const u16* bbase = Uf + (size_t)(128 * h2) * HD;
        #pragma unroll
        for (int ks = 0; ks < 8; ++ks) {
            const v8s a0 = *(const v8s*)(abase + (size_t)r15 * HD + ks * 32 + g * 8);
            const v8s a1 = *(const v8s*)(abase + (size_t)(16 + r15) * HD + ks * 32 + g * 8);
            #pragma unroll
            for (int j = 0; j < 8; ++j) {
                const v8s b = *(const v8s*)(bbase + (size_t)(16 * j + r15) * HD + ks * 32 + g * 8);
                acc2[0][j] = __builtin_amdgcn_mfma_f32_16x16x32_bf16(a0, b, acc2[0][j], 0, 0, 0);
                acc2[1][j] = __builtin_amdgcn_mfma_f32_16x16x32_bf16(a1, b, acc2[1][j], 0, 0, 0);
            }
        }
        #pragma unroll
        for (int tau = 0; tau < 2; ++tau) {
            const int crow = 2 * m0 + 32 * mt + 16 * tau + 4 * g;
            #pragma unroll
            for (int j = 0; j < 8; ++j) {
                const int ch = 16 * (8 * h2 + j) + r15;
                const float fb = U_f_b[ch];
                #pragma unroll
                for (int q = 0; q < 2; ++q) {
                    const float f0 = sigm_(acc2[tau][j][2 * q] + fb);
                    const float f1 = sigm_(acc2[tau][j][2 * q + 1] + fb);
                    const float c0 = c_prev[(size_t)(crow + 2 * q) * HD + ch];
                    const float c1 = c_prev[(size_t)(crow + 2 * q + 1) * HD + ch];
                    cinreg[tau][j][q] = fmaf(f0, c0, f1 * c1);
                }
            }
        }
    }

    // ---- GEMM1 (p-split) + fused LSTM epilogue ----
    #pragma unroll 1
    for (int p = 0; p < 2; ++p) {
        v4f acc1[3][4];
        #pragma unroll
        for (int c = 0; c < 3; ++c)
            #pragma unroll
            for (int t = 0; t < 4; ++t)
                acc1[c][t] = (v4f){0.f, 0.f, 0.f, 0.f};

        constexpr int KS = LEAF ? 8 : 16;
        #pragma unroll
        for (int ks = 0; ks < KS; ++ks) {
            const v8s a1 = *(const v8s*)&xcat[(16 * mt + r15) * XS + ks * 32 + g * 8];
            #pragma unroll
            for (int c = 0; c < 3; ++c) {
                #pragma unroll
                for (int t = 0; t < 4; ++t) {
                    const int nn = 16 * c + 8 * h2 + 4 * p + t;   // i/o/u panel tile
                    const v8s b = *(const v8s*)(Wcat + (size_t)(16 * nn + r15) * 512 + ks * 32 + g * 8);
                    acc1[c][t] = __builtin_amdgcn_mfma_f32_16x16x32_bf16(a1, b, acc1[c][t], 0, 0, 0);
                }
            }
        }

        #pragma unroll
        for (int t = 0; t < 4; ++t) {
            const int n  = 8 * h2 + 4 * p + t;
            const int ch = 16 * n + r15;
            const float bi = b_iou[ch];
            const float bo = b_iou[HD + ch];
            const float bu = b_iou[2 * HD + ch];
            float hacc = 0.f;
            #pragma unroll
            for (int r = 0; r < 4; ++r) {
                const int ml = 16 * mt + 4 * g + r;
                const float iv = sigm_(acc1[0][t][r] + bi);
                const float ov = sigm_(acc1[1][t][r] + bo);
                const float uv = tanh_(acc1[2][t][r] + bu);
                float ci = 0.f;
                if constexpr (!LEAF) {
                    // producer lane for node 4g+r: g' = (2g + (r>>1)) & 3,
                    // tau = g>>1, q = r&1  (round-2-verified mapping)
                    const int j   = 4 * p + t;
                    const int src = 16 * ((2 * g + (r >> 1)) & 3) + r15;
                    const float va = __shfl(cinreg[0][j][r & 1], src, 64);
                    const float vb = __shfl(cinreg[1][j][r & 1], src, 64);
                    ci = (g >= 2) ? vb : va;
                }
                const float cn = fmaf(iv, uv, ci);
                const float hn = ov * tanh_(cn);
                const size_t m = (size_t)(m0 + ml);
                h_cur[m * HD + ch] = f2bf(hn);
                c_cur[m * HD + ch] = cn;
                if (level >= 5) hacc += hn;
                else atomicAdd(&hsum[((m0 + ml) >> level) * HD + ch], hn);
            }
            if (level >= 5) atomicAdd(&hsum[(m0 >> level) * HD + ch], hacc);
        }
    }
}

// out[tree][c] = (hsum[tree]/NPT) . lin_w[c] + lin_b[c]
__global__ __launch_bounds__(128) void final_kernel(
    const float* __restrict__ hsum, const float* __restrict__ lin_w,
    const float* __restrict__ lin_b, float* __restrict__ out)
{
    __shared__ float hg[HD];
    const int tree = blockIdx.x;
    for (int j = threadIdx.x; j < HD; j += 128)
        hg[j] = hsum[tree * HD + j] * (1.0f / (float)NPT);
    __syncthreads();
    const int c = threadIdx.x;
    if (c < NCLS) {
        const float* wr = lin_w + (size_t)c * HD;
        float acc = lin_b[c];
        #pragma unroll 4
        for (int j = 0; j < HD; ++j)
            acc = fmaf(hg[j], wr[j], acc);
        out[tree * NCLS + c] = acc;
    }
}

extern "C" void kernel_launch(void* const* d_in, const int* in_sizes, int n_in,
                              void* d_out, int out_size, void* d_ws, size_t ws_size,
                              hipStream_t stream)
{
    const int*   feat  = (const int*)d_in[0];
    const float* emb   = (const float*)d_in[1];
    const float* W_iou = (const float*)d_in[2];
    const float* U_iou = (const float*)d_in[3];
    const float* b_iou = (const float*)d_in[4];
    const float* U_f_w = (const float*)d_in[5];
    const float* U_f_b = (const float*)d_in[6];
    const float* lin_w = (const float*)d_in[7];
    const float* lin_b = (const float*)d_in[8];
    float* out = (float*)d_out;

    const int emb_elems = in_sizes[1];          // V * 256

    char* ws = (char*)d_ws;
    size_t off = 0;
    auto alloc = [&](size_t bytes) -> void* {
        void* p = ws + off;
        off += (bytes + 255) & ~(size_t)255;
        return p;
    };
    u16*   Wcat   = (u16*)alloc((size_t)H3 * 512 * 2);
    u16*   Uf     = (u16*)alloc((size_t)HD * HD * 2);
    u16*   emb_bf = (u16*)alloc((size_t)emb_elems * 2);
    float* hsum   = (float*)alloc((size_t)NTREES * HD * 4);
    u16*   hA     = (u16*)alloc((size_t)65536 * HD * 2);
    u16*   hB     = (u16*)alloc((size_t)32768 * HD * 2);
    float* cA     = (float*)alloc((size_t)65536 * HD * 4);
    float* cB     = (float*)alloc((size_t)32768 * HD * 4);
    (void)ws_size; (void)n_in; (void)out_size;

    prep_weights<<<768, 256, 0, stream>>>(W_iou, U_iou, U_f_w, Wcat, Uf);
    const int n4 = emb_elems / 4;
    emb_to_bf16<<<(n4 + 255) / 256, 256, 0, stream>>>(emb, emb_bf, n4);
    hipMemsetAsync(hsum, 0, (size_t)NTREES * HD * 4, stream);

    for (int l = TDEPTH - 1; l >= 0; --l) {
        const int blocks = 2 << l;              // (64 << l) / 32
        const int p      = (TDEPTH - 1 - l) & 1;
        u16*   hc = p ? hB : hA;
        float* cc = p ? cB : cA;
        const u16*   hp = p ? hA : hB;
        const float* cp = p ? cA : cB;
        if (l == TDEPTH - 1) {
            level_kernel<true><<<blocks, 256, 0, stream>>>(
                feat, emb_bf, Wcat, Uf, b_iou, U_f_b,
                nullptr, nullptr, hc, cc, hsum, l);
        } else {
            level_kernel<false><<<blocks, 256, 0, stream>>>(
                feat, emb_bf, Wcat, Uf, b_iou, U_f_b,
                hp, cp, hc, cc, hsum, l);
        }
    }

    final_kernel<<<NTREES, 128, 0, stream>>>(hsum, lin_w, lin_b, out);
}

// Round 8
// 1054.993 us; speedup vs baseline: 1.4199x; 1.4199x over previous
//
#include <hip/hip_runtime.h>
#include <hip/hip_bf16.h>
#include <math.h>

// GraphLSTM (binary TreeLSTM), 64 trees x 2047 nodes, H=E=256, C=104.
// Round 8: round-2 structure (all operands LDS-staged, high MFMA:load ratio)
// at 2 blocks/CU. Internal: BM=32, 8 waves, LDS {xcat 32x520, hch 64x264}
// = 67 KB; GEMM2 4Mx2N per wave from LDS; cin via f32 overlay (stride 260)
// on hch; 3 barriers. Leaf: BM=64, xcat only (33.8 KB). launch_bounds(512,4).

#define NTREES 64
#define TDEPTH 11
#define NPT    2047
#define HD     256
#define H3     768
#define NCLS   104

typedef short v8s __attribute__((ext_vector_type(8)));
typedef float v4f __attribute__((ext_vector_type(4)));
typedef unsigned short u16;
typedef unsigned int   u32;

__device__ __forceinline__ float bfLo(u32 u) {
    return __builtin_bit_cast(float, u << 16);
}
__device__ __forceinline__ float bfHi(u32 u) {
    return __builtin_bit_cast(float, u & 0xffff0000u);
}
__device__ __forceinline__ u16 f2bf(float f) {
    return __builtin_bit_cast(u16, __float2bfloat16(f));
}
__device__ __forceinline__ u32 pk2(float lo, float hi) {
    return (u32)f2bf(lo) | ((u32)f2bf(hi) << 16);
}
__device__ __forceinline__ float sigm_(float x) {
    return __builtin_amdgcn_rcpf(1.0f + __expf(-x));
}
__device__ __forceinline__ float tanh_(float x) {
    return 1.0f - 2.0f * __builtin_amdgcn_rcpf(__expf(2.0f * x) + 1.0f);
}

// Wcat[n][0:256]=W_iou[n][:], Wcat[n][256:512]=U_iou[n][:] (bf16). Uf bf16.
__global__ __launch_bounds__(256) void prep_weights(
    const float* __restrict__ W_iou, const float* __restrict__ U_iou,
    const float* __restrict__ U_f_w,
    u16* __restrict__ Wcat, u16* __restrict__ Uf)
{
    int tid = blockIdx.x * 256 + threadIdx.x;   // 0..196607
    int n  = tid >> 8;
    int c0 = (tid & 255) * 2;
    float a, b;
    if (c0 < 256) { a = W_iou[n * 256 + c0];       b = W_iou[n * 256 + c0 + 1]; }
    else          { a = U_iou[n * 256 + c0 - 256]; b = U_iou[n * 256 + c0 - 255]; }
    *(u32*)&Wcat[n * 512 + c0] = pk2(a, b);
    if (tid < 32768) {
        int jj = tid >> 7, cc = (tid & 127) * 2;
        *(u32*)&Uf[jj * 256 + cc] = pk2(U_f_w[jj * 256 + cc], U_f_w[jj * 256 + cc + 1]);
    }
}

__global__ __launch_bounds__(256) void emb_to_bf16(
    const float* __restrict__ emb, u16* __restrict__ emb_bf, int n4)
{
    int i = blockIdx.x * 256 + threadIdx.x;
    if (i < n4) {
        const float4 v = ((const float4*)emb)[i];
        uint2 o;
        o.x = pk2(v.x, v.y);
        o.y = pk2(v.z, v.w);
        ((uint2*)emb_bf)[i] = o;
    }
}

// 512 threads = 8 waves. Internal: 32 nodes/block; leaf: 64 nodes/block.
// GEMM1: [BM, 768] = Xcat[BM, 512] @ Wcat^T (leaf: K=256), p-split N halves.
// GEMM2 (internal): [64, 256] = hch @ Uf^T from LDS; wave w: 4 M-tiles x
// N-tiles {2w, 2w+1}; cin -> f32 overlay on hch (stride 260).
template<bool LEAF>
__global__ __launch_bounds__(512, 4) void level_kernel(
    const int* __restrict__ feat, const u16* __restrict__ emb_bf,
    const u16* __restrict__ Wcat, const u16* __restrict__ Uf,
    const float* __restrict__ b_iou, const float* __restrict__ U_f_b,
    const u16* __restrict__ h_prev, const float* __restrict__ c_prev,
    u16* __restrict__ h_cur, float* __restrict__ c_cur,
    float* __restrict__ hsum, int level)
{
    constexpr int BM = LEAF ? 64 : 32;
    constexpr int XS = LEAF ? 264 : 520;      // xcat row stride (u16)
    constexpr int CS = 260;                   // cin row stride (f32)
    __shared__ __align__(16) u16 xcat[BM * XS];
    __shared__ __align__(16) u16 hch[LEAF ? 8 : 64 * 264];

    const int tid = threadIdx.x;
    const int wv  = tid >> 6;       // 0..7
    const int ln  = tid & 63;
    const int g   = ln >> 4;
    const int r15 = ln & 15;
    const int m0  = blockIdx.x * BM;
    const int L   = 1 << level;

    // ---- stage X (bf16 emb rows): wave w -> rows (BM/8)*w .. +BM/8-1 ----
    constexpr int XR = BM / 8;
    #pragma unroll
    for (int it = 0; it < XR; ++it) {
        const int r    = XR * wv + it;
        const int m    = m0 + r;
        const int tree = m >> level;
        const int pos  = m & (L - 1);
        const int f    = feat[tree * NPT + (L - 1) + pos];
        const uint2 v = *(const uint2*)(emb_bf + (size_t)f * HD + ln * 4);
        *(uint2*)&xcat[r * XS + ln * 4] = v;
    }

    if constexpr (!LEAF) {
        // ---- stage hch: wave w -> child rows 8w..8w+7 (2 rows/iter) ----
        #pragma unroll
        for (int it = 0; it < 4; ++it) {
            const int r = 8 * wv + 2 * it + (ln >> 5);
            const v8s hv = *(const v8s*)(h_prev + (size_t)(2 * m0 + r) * HD + (ln & 31) * 8);
            *(v8s*)&hch[r * 264 + (ln & 31) * 8] = hv;
        }
    }
    __syncthreads();

    if constexpr (!LEAF) {
        // ---- Hsum = bf16(h_l + h_r) from LDS hch -> xcat[:,256:512] ----
        #pragma unroll
        for (int it = 0; it < 4; ++it) {
            const int r = 4 * wv + it;
            const uint2 a = *(const uint2*)&hch[(2 * r) * 264 + ln * 4];
            const uint2 b = *(const uint2*)&hch[(2 * r + 1) * 264 + ln * 4];
            uint2 o;
            o.x = pk2(bfLo(a.x) + bfLo(b.x), bfHi(a.x) + bfHi(b.x));
            o.y = pk2(bfLo(a.y) + bfLo(b.y), bfHi(a.y) + bfHi(b.y));
            *(uint2*)&xcat[r * XS + 256 + ln * 4] = o;
        }

        // ---- GEMM2: 4 M-tiles x N-tiles {2wv, 2wv+1}, A from LDS ----
        v4f acc2[4][2];
        #pragma unroll
        for (int m = 0; m < 4; ++m)
            #pragma unroll
            for (int j = 0; j < 2; ++j)
                acc2[m][j] = (v4f){0.f, 0.f, 0.f, 0.f};

        #pragma unroll
        for (int ks = 0; ks < 8; ++ks) {
            v8s a2[4];
            #pragma unroll
            for (int m = 0; m < 4; ++m)
                a2[m] = *(const v8s*)&hch[(16 * m + r15) * 264 + ks * 32 + g * 8];
            #pragma unroll
            for (int j = 0; j < 2; ++j) {
                const v8s b = *(const v8s*)(Uf + (size_t)(16 * (2 * wv + j) + r15) * HD + ks * 32 + g * 8);
                #pragma unroll
                for (int m = 0; m < 4; ++m)
                    acc2[m][j] = __builtin_amdgcn_mfma_f32_16x16x32_bf16(a2[m], b, acc2[m][j], 0, 0, 0);
            }
        }
        __syncthreads();   // all hch reads done; xcat Hsum visible

        // ---- f-epilogue: cin -> f32 overlay on hch (stride 260 f32) ----
        float* cinL = (float*)hch;
        #pragma unroll
        for (int j = 0; j < 2; ++j) {
            const int ch = 16 * (2 * wv + j) + r15;
            const float fb = U_f_b[ch];
            #pragma unroll
            for (int m = 0; m < 4; ++m) {
                #pragma unroll
                for (int q = 0; q < 2; ++q) {
                    const int cr = 2 * m0 + 16 * m + 4 * g + 2 * q;
                    const float f0 = sigm_(acc2[m][j][2 * q] + fb);
                    const float f1 = sigm_(acc2[m][j][2 * q + 1] + fb);
                    const float c0 = c_prev[(size_t)cr * HD + ch];
                    const float c1 = c_prev[(size_t)(cr + 1) * HD + ch];
                    cinL[(8 * m + 2 * g + q) * CS + ch] = fmaf(f0, c0, f1 * c1);
                }
            }
        }
        __syncthreads();   // cin visible to all
    }

    // ---- GEMM1 (p-split) + fused LSTM epilogue ----
    const float* cinR = (const float*)hch;
    constexpr int NMT = LEAF ? 4 : 2;
    #pragma unroll 1
    for (int p = 0; p < 2; ++p) {
        v4f acc1[3][NMT];
        #pragma unroll
        for (int c = 0; c < 3; ++c)
            #pragma unroll
            for (int mt = 0; mt < NMT; ++mt)
                acc1[c][mt] = (v4f){0.f, 0.f, 0.f, 0.f};

        constexpr int KS = LEAF ? 8 : 16;
        #pragma unroll
        for (int ks = 0; ks < KS; ++ks) {
            v8s a1[NMT];
            #pragma unroll
            for (int mt = 0; mt < NMT; ++mt)
                a1[mt] = *(const v8s*)&xcat[(16 * mt + r15) * XS + ks * 32 + g * 8];
            #pragma unroll
            for (int c = 0; c < 3; ++c) {
                const int nn = 16 * c + wv + 8 * p;   // i / o / u panel tile
                const v8s b = *(const v8s*)(Wcat + (size_t)(16 * nn + r15) * 512 + ks * 32 + g * 8);
                #pragma unroll
                for (int mt = 0; mt < NMT; ++mt)
                    acc1[c][mt] = __builtin_amdgcn_mfma_f32_16x16x32_bf16(a1[mt], b, acc1[c][mt], 0, 0, 0);
            }
        }

        const int n  = wv + 8 * p;
        const int ch = 16 * n + r15;
        const float bi = b_iou[ch];
        const float bo = b_iou[HD + ch];
        const float bu = b_iou[2 * HD + ch];
        float hacc = 0.f;
        #pragma unroll
        for (int mt = 0; mt < NMT; ++mt) {
            #pragma unroll
            for (int r = 0; r < 4; ++r) {
                const int ml = 16 * mt + 4 * g + r;
                const float iv = sigm_(acc1[0][mt][r] + bi);
                const float ov = sigm_(acc1[1][mt][r] + bo);
                const float uv = tanh_(acc1[2][mt][r] + bu);
                float ci = 0.f;
                if constexpr (!LEAF) ci = cinR[ml * CS + ch];
                const float cn = fmaf(iv, uv, ci);
                const float hn = ov * tanh_(cn);
                const size_t m = (size_t)(m0 + ml);
                h_cur[m * HD + ch] = f2bf(hn);
                c_cur[m * HD + ch] = cn;
                if (LEAF || level >= 5) hacc += hn;
                else atomicAdd(&hsum[((m0 + ml) >> level) * HD + ch], hn);
            }
        }
        if (LEAF || level >= 5) atomicAdd(&hsum[(m0 >> level) * HD + ch], hacc);
    }
}

// out[tree][c] = (hsum[tree]/NPT) . lin_w[c] + lin_b[c]
__global__ __launch_bounds__(128) void final_kernel(
    const float* __restrict__ hsum, const float* __restrict__ lin_w,
    const float* __restrict__ lin_b, float* __restrict__ out)
{
    __shared__ float hg[HD];
    const int tree = blockIdx.x;
    for (int j = threadIdx.x; j < HD; j += 128)
        hg[j] = hsum[tree * HD + j] * (1.0f / (float)NPT);
    __syncthreads();
    const int c = threadIdx.x;
    if (c < NCLS) {
        const float* wr = lin_w + (size_t)c * HD;
        float acc = lin_b[c];
        #pragma unroll 4
        for (int j = 0; j < HD; ++j)
            acc = fmaf(hg[j], wr[j], acc);
        out[tree * NCLS + c] = acc;
    }
}

extern "C" void kernel_launch(void* const* d_in, const int* in_sizes, int n_in,
                              void* d_out, int out_size, void* d_ws, size_t ws_size,
                              hipStream_t stream)
{
    const int*   feat  = (const int*)d_in[0];
    const float* emb   = (const float*)d_in[1];
    const float* W_iou = (const float*)d_in[2];
    const float* U_iou = (const float*)d_in[3];
    const float* b_iou = (const float*)d_in[4];
    const float* U_f_w = (const float*)d_in[5];
    const float* U_f_b = (const float*)d_in[6];
    const float* lin_w = (const float*)d_in[7];
    const float* lin_b = (const float*)d_in[8];
    float* out = (float*)d_out;

    const int emb_elems = in_sizes[1];          // V * 256

    char* ws = (char*)d_ws;
    size_t off = 0;
    auto alloc = [&](size_t bytes) -> void* {
        void* p = ws + off;
        off += (bytes + 255) & ~(size_t)255;
        return p;
    };
    u16*   Wcat   = (u16*)alloc((size_t)H3 * 512 * 2);
    u16*   Uf     = (u16*)alloc((size_t)HD * HD * 2);
    u16*   emb_bf = (u16*)alloc((size_t)emb_elems * 2);
    float* hsum   = (float*)alloc((size_t)NTREES * HD * 4);
    u16*   hA     = (u16*)alloc((size_t)65536 * HD * 2);
    u16*   hB     = (u16*)alloc((size_t)32768 * HD * 2);
    float* cA     = (float*)alloc((size_t)65536 * HD * 4);
    float* cB     = (float*)alloc((size_t)32768 * HD * 4);
    (void)ws_size; (void)n_in; (void)out_size;

    prep_weights<<<768, 256, 0, stream>>>(W_iou, U_iou, U_f_w, Wcat, Uf);
    const int n4 = emb_elems / 4;
    emb_to_bf16<<<(n4 + 255) / 256, 256, 0, stream>>>(emb, emb_bf, n4);
    hipMemsetAsync(hsum, 0, (size_t)NTREES * HD * 4, stream);

    for (int l = TDEPTH - 1; l >= 0; --l) {
        const int p = (TDEPTH - 1 - l) & 1;
        u16*   hc = p ? hB : hA;
        float* cc = p ? cB : cA;
        const u16*   hp = p ? hA : hB;
        const float* cp = p ? cA : cB;
        if (l == TDEPTH - 1) {
            level_kernel<true><<<1024, 512, 0, stream>>>(    // 65536 / 64
                feat, emb_bf, Wcat, Uf, b_iou, U_f_b,
                nullptr, nullptr, hc, cc, hsum, l);
        } else {
            level_kernel<false><<<2 << l, 512, 0, stream>>>( // (64<<l) / 32
                feat, emb_bf, Wcat, Uf, b_iou, U_f_b,
                hp, cp, hc, cc, hsum, l);
        }
    }

    final_kernel<<<NTREES, 128, 0, stream>>>(hsum, lin_w, lin_b, out);
}